// Round 2
// baseline (9741.624 us; speedup 1.0000x reference)
//
#include <hip/hip_runtime.h>
#include <math.h>

#define NTOK   32768
#define DIMS   128
#define QST    8
#define KC     1024

#define SZ_QUANT (NTOK*DIMS)
#define SZ_CODES (NTOK*QST)
#define SZ_W     (QST*KC*DIMS)
#define OFF_CODES (SZ_QUANT)
#define OFF_LOSS  (OFF_CODES + SZ_CODES)
#define OFF_W     (OFF_LOSS + 1)
#define OFF_RM    (OFF_W + SZ_W)
#define OFF_CC    (OFF_RM + SZ_W)

// Transpose w[s][k][d] -> wt[s][d][k] so B loads are contiguous over codes.
__global__ void rvq_transpose(const float* __restrict__ w, float* __restrict__ wt) {
    __shared__ float tile[32][33];
    int b  = blockIdx.x;            // 8 stages * 32 ktiles * 4 dtiles = 1024
    int s  = b >> 7;
    int kt = (b >> 2) & 31;
    int dt = b & 3;
    const float* wi = w  + (size_t)s * KC * DIMS;
    float*       wo = wt + (size_t)s * KC * DIMS;
    int c  = threadIdx.x & 31;
    int r8 = threadIdx.x >> 5;
    #pragma unroll
    for (int rep = 0; rep < 4; ++rep) {
        int row = rep * 8 + r8;     // code-local
        tile[row][c] = wi[(size_t)(kt * 32 + row) * DIMS + dt * 32 + c];
    }
    __syncthreads();
    #pragma unroll
    for (int rep = 0; rep < 4; ++rep) {
        int row = rep * 8 + r8;     // d-local
        wo[(size_t)(dt * 32 + row) * KC + kt * 32 + c] = tile[c][row];
    }
}

// ||w||^2 per code row, all stages. One wave per row.
__global__ void rvq_wsq(const float* __restrict__ w, float* __restrict__ wsq) {
    int row  = blockIdx.x * 4 + (threadIdx.x >> 6);
    int lane = threadIdx.x & 63;
    const float* wr = w + (size_t)row * DIMS;
    float a = wr[lane];
    float b = wr[lane + 64];
    float v = a * a + b * b;
    #pragma unroll
    for (int off = 32; off > 0; off >>= 1) v += __shfl_down(v, off, 64);
    if (lane == 0) wsq[row] = v;
}

// One stage: 32 tokens/block, 1024 blocks. A-tile in LDS (swizzled [d][tok]),
// B (wt) streamed from global (L1/L2-hot), no barriers in the FMA loop.
__global__ __launch_bounds__(256, 4)
void rvq_stage(const float* __restrict__ rin,
               float* __restrict__ rout,
               const float* __restrict__ wst,     // row-major w of this stage [K][D]
               const float* __restrict__ wtst,    // transposed w of this stage [D][K]
               const float* __restrict__ wsqst,   // ||w||^2 [K]
               float* __restrict__ codes_out,
               float* __restrict__ rm_acc,
               float* __restrict__ cc_acc,
               int stage)
{
    __shared__ float A[DIMS * 32];        // 16 KiB, [d][tok] XOR-quad swizzled
    __shared__ float red_d[4 * 32];
    __shared__ int   red_k[4 * 32];
    __shared__ int   kbest[32];

    const int t    = threadIdx.x;
    const int tg   = t & 7;               // token group: tokens 4*tg .. 4*tg+3
    const int cg   = t >> 3;              // code group: 8 codes, 32 groups
    const int tok0 = blockIdx.x * 32;

    // ---- stage A: coalesced read, swizzled transposed write
    #pragma unroll
    for (int q = 0; q < 4; ++q) {
        int idx = q * 256 + t;            // 1024 float4s
        int tok = idx >> 5;
        int dq  = idx & 31;
        float4 v = *reinterpret_cast<const float4*>(rin + (size_t)(tok0 + tok) * DIMS + dq * 4);
        int base = ((((tok >> 2) ^ dq) & 7) << 2) + (tok & 3);
        A[(dq * 4 + 0) * 32 + base] = v.x;
        A[(dq * 4 + 1) * 32 + base] = v.y;
        A[(dq * 4 + 2) * 32 + base] = v.z;
        A[(dq * 4 + 3) * 32 + base] = v.w;
    }
    __syncthreads();

    float best[4];
    int   bkst[4];
    #pragma unroll
    for (int i = 0; i < 4; ++i) { best[i] = INFINITY; bkst[i] = 0; }

    for (int ct = 0; ct < 4; ++ct) {                  // 4 passes of 256 codes
        const int ccol = ct * 256 + cg * 8;           // this thread's 8 codes
        const float* bp = wtst + ccol;
        float acc[4][8];
        #pragma unroll
        for (int i = 0; i < 4; ++i)
            #pragma unroll
            for (int j = 0; j < 8; ++j) acc[i][j] = 0.0f;

        #pragma unroll 2
        for (int dq = 0; dq < 32; ++dq) {
            const int p = ((tg ^ dq) & 7) << 2;
            #pragma unroll
            for (int c = 0; c < 4; ++c) {
                const int d = dq * 4 + c;
                float4 av = *reinterpret_cast<const float4*>(A + d * 32 + p);
                float4 b0 = *reinterpret_cast<const float4*>(bp + (size_t)d * KC);
                float4 b1 = *reinterpret_cast<const float4*>(bp + (size_t)d * KC + 4);
                const float a[4]  = {av.x, av.y, av.z, av.w};
                const float bb[8] = {b0.x, b0.y, b0.z, b0.w, b1.x, b1.y, b1.z, b1.w};
                #pragma unroll
                for (int i = 0; i < 4; ++i)
                    #pragma unroll
                    for (int j = 0; j < 8; ++j)
                        acc[i][j] = fmaf(a[i], bb[j], acc[i][j]);
            }
        }

        // dist = ||w||^2 - 2*dot ; running argmin (ascending code order)
        float4 wq0 = *reinterpret_cast<const float4*>(wsqst + ccol);
        float4 wq1 = *reinterpret_cast<const float4*>(wsqst + ccol + 4);
        const float wqa[8] = {wq0.x, wq0.y, wq0.z, wq0.w, wq1.x, wq1.y, wq1.z, wq1.w};
        #pragma unroll
        for (int j = 0; j < 8; ++j) {
            int code = ccol + j;
            #pragma unroll
            for (int i = 0; i < 4; ++i) {
                float dist = wqa[j] - 2.0f * acc[i][j];
                if (dist < best[i]) { best[i] = dist; bkst[i] = code; }
            }
        }
    }

    // ---- in-wave argmin reduction over the 8 code-groups sharing each tg
    #pragma unroll
    for (int i = 0; i < 4; ++i) {
        float bd = best[i];
        int   bk = bkst[i];
        #pragma unroll
        for (int m = 8; m < 64; m <<= 1) {
            float od = __shfl_xor(bd, m, 64);
            int   ok = __shfl_xor(bk, m, 64);
            if (od < bd || (od == bd && ok < bk)) { bd = od; bk = ok; }
        }
        best[i] = bd; bkst[i] = bk;
    }
    const int wid = t >> 6;
    if ((t & 56) == 0) {                   // one lane per (wave, tg)
        #pragma unroll
        for (int i = 0; i < 4; ++i) {
            red_d[wid * 32 + tg * 4 + i] = best[i];
            red_k[wid * 32 + tg * 4 + i] = bkst[i];
        }
    }
    __syncthreads();
    if (t < 32) {
        float bd = red_d[t];
        int   bk = red_k[t];
        #pragma unroll
        for (int w = 1; w < 4; ++w) {
            float od = red_d[w * 32 + t];
            int   ok = red_k[w * 32 + t];
            if (od < bd || (od == bd && ok < bk)) { bd = od; bk = ok; }
        }
        kbest[t] = bk;
        codes_out[(size_t)(tok0 + t) * QST + stage] = (float)bk;
        atomicAdd(cc_acc + bk, 1.0f);
    }
    __syncthreads();

    // ---- update: rm_acc[k] += r_old (re-read from global, L2-hot); r_new = r_old - w[k]
    #pragma unroll
    for (int it = 0; it < 4; ++it) {
        int idx = it * 256 + t;            // 1024 float4s
        int tok = idx >> 5;
        int dq  = idx & 31;
        int k   = kbest[tok];
        float4 rv = *reinterpret_cast<const float4*>(rin + (size_t)(tok0 + tok) * DIMS + dq * 4);
        float4 wv = *reinterpret_cast<const float4*>(wst + (size_t)k * DIMS + dq * 4);
        float* rmp = rm_acc + (size_t)k * DIMS + dq * 4;
        atomicAdd(rmp + 0, rv.x);
        atomicAdd(rmp + 1, rv.y);
        atomicAdd(rmp + 2, rv.z);
        atomicAdd(rmp + 3, rv.w);
        float4 o;
        o.x = rv.x - wv.x; o.y = rv.y - wv.y; o.z = rv.z - wv.z; o.w = rv.w - wv.w;
        *reinterpret_cast<float4*>(rout + (size_t)(tok0 + tok) * DIMS + dq * 4) = o;
    }
}

// quantized = x - r (in place over the r buffer) + commitment-loss partial sums
__global__ void rvq_quant_loss(const float* __restrict__ x,
                               float* __restrict__ rq,
                               float* __restrict__ loss_acc) {
    __shared__ float ws[4];
    int tid = blockIdx.x * 256 + threadIdx.x;
    float lsum = 0.0f;
    #pragma unroll
    for (int rep = 0; rep < 4; ++rep) {
        size_t q = (size_t)tid + (size_t)rep * 262144;
        float4 rv = *reinterpret_cast<float4*>(rq + q * 4);
        float4 xv = *reinterpret_cast<const float4*>(x + q * 4);
        lsum += rv.x*rv.x + rv.y*rv.y + rv.z*rv.z + rv.w*rv.w;
        float4 o;
        o.x = xv.x - rv.x; o.y = xv.y - rv.y; o.z = xv.z - rv.z; o.w = xv.w - rv.w;
        *reinterpret_cast<float4*>(rq + q * 4) = o;
    }
    #pragma unroll
    for (int off = 32; off > 0; off >>= 1) lsum += __shfl_down(lsum, off, 64);
    if ((threadIdx.x & 63) == 0) ws[threadIdx.x >> 6] = lsum;
    __syncthreads();
    if (threadIdx.x == 0) atomicAdd(loss_acc, ws[0] + ws[1] + ws[2] + ws[3]);
}

__global__ void rvq_fin_cc(const float* __restrict__ cc_in,
                           float* __restrict__ cc_io,
                           const float* __restrict__ loss_acc,
                           float* __restrict__ loss_out) {
    int i = blockIdx.x * 256 + threadIdx.x;   // 8192
    float accv = cc_io[i];
    cc_io[i] = cc_in[i] * 0.99f + (accv / 32768.0f) * 0.01f;
    if (i == 0) loss_out[0] = loss_acc[0] / (float)(NTOK * DIMS);
}

__global__ void rvq_fin_rmw(const float* __restrict__ rm_in,
                            float* __restrict__ rm_io,
                            float* __restrict__ w_out,
                            const float* __restrict__ cc_fin) {
    int i = blockIdx.x * 256 + threadIdx.x;   // 1,048,576
    float accv = rm_io[i];
    float nrm = rm_in[i] * 0.99f + (accv / 32768.0f) * 0.01f;
    rm_io[i] = nrm;
    w_out[i] = nrm / (1e-10f + cc_fin[i >> 7]);
}

extern "C" void kernel_launch(void* const* d_in, const int* in_sizes, int n_in,
                              void* d_out, int out_size, void* d_ws, size_t ws_size,
                              hipStream_t stream) {
    const float* x   = (const float*)d_in[0];
    const float* w   = (const float*)d_in[1];
    const float* rm  = (const float*)d_in[2];
    const float* cc  = (const float*)d_in[3];
    float* out   = (float*)d_out;
    float* quant = out;                    // doubles as the residual buffer
    float* codes = out + OFF_CODES;
    float* loss  = out + OFF_LOSS;
    float* wout  = out + OFF_W;            // used as wt scratch until rvq_fin_rmw
    float* rmout = out + OFF_RM;
    float* ccout = out + OFF_CC;
    float* lacc  = (float*)d_ws;
    float* wsq   = (float*)d_ws + 4;
    float* wt    = wout;

    hipMemsetAsync(rmout, 0, (size_t)(SZ_W + QST * KC) * sizeof(float), stream);
    hipMemsetAsync(d_ws, 0, 16, stream);

    rvq_transpose<<<1024, 256, 0, stream>>>(w, wt);
    rvq_wsq<<<QST * KC / 4, 256, 0, stream>>>(w, wsq);

    for (int s = 0; s < QST; ++s) {
        const float* rin = (s == 0) ? x : quant;
        rvq_stage<<<NTOK / 32, 256, 0, stream>>>(
            rin, quant,
            w  + (size_t)s * KC * DIMS,
            wt + (size_t)s * KC * DIMS,
            wsq + (size_t)s * KC,
            codes,
            rmout + (size_t)s * KC * DIMS,
            ccout + (size_t)s * KC,
            s);
    }

    rvq_quant_loss<<<1024, 256, 0, stream>>>(x, quant, lacc);
    rvq_fin_cc<<<QST * KC / 256, 256, 0, stream>>>(cc, ccout, lacc, loss);
    rvq_fin_rmw<<<SZ_W / 256, 256, 0, stream>>>(rm, rmout, wout, ccout);
}

// Round 4
// 5273.600 us; speedup vs baseline: 1.8472x; 1.8472x over previous
//
#include <hip/hip_runtime.h>
#include <math.h>

#define NTOK   32768
#define DIMS   128
#define QST    8
#define KC     1024

#define SZ_QUANT (NTOK*DIMS)
#define SZ_CODES (NTOK*QST)
#define SZ_W     (QST*KC*DIMS)
#define OFF_CODES (SZ_QUANT)
#define OFF_LOSS  (OFF_CODES + SZ_CODES)
#define OFF_W     (OFF_LOSS + 1)
#define OFF_RM    (OFF_W + SZ_W)
#define OFF_CC    (OFF_RM + SZ_W)

// d_ws float layout: [0..15] lacc etc; [16 .. 16+8192) wsq; [8208 ..) replica accumulators
#define WS_WSQ 16
#define WS_REP (16 + QST*KC)
#define REPSTRIDE ((size_t)SZ_W + QST*KC)   // floats per extra replica (rm + cc)

typedef __attribute__((address_space(3))) float  lds_f;
typedef const __attribute__((address_space(1))) float gbl_f;

// Transpose w[s][k][d] -> wt[s][d][k]
__global__ void rvq_transpose(const float* __restrict__ w, float* __restrict__ wt) {
    __shared__ float tile[32][33];
    int b  = blockIdx.x;            // 8 stages * 32 ktiles * 4 dtiles = 1024
    int s  = b >> 7;
    int kt = (b >> 2) & 31;
    int dt = b & 3;
    const float* wi = w  + (size_t)s * KC * DIMS;
    float*       wo = wt + (size_t)s * KC * DIMS;
    int c  = threadIdx.x & 31;
    int r8 = threadIdx.x >> 5;
    #pragma unroll
    for (int rep = 0; rep < 4; ++rep) {
        int row = rep * 8 + r8;
        tile[row][c] = wi[(size_t)(kt * 32 + row) * DIMS + dt * 32 + c];
    }
    __syncthreads();
    #pragma unroll
    for (int rep = 0; rep < 4; ++rep) {
        int row = rep * 8 + r8;
        wo[(size_t)(dt * 32 + row) * KC + kt * 32 + c] = tile[c][row];
    }
}

// ||w||^2 per code row
__global__ void rvq_wsq(const float* __restrict__ w, float* __restrict__ wsq) {
    int row  = blockIdx.x * 4 + (threadIdx.x >> 6);
    int lane = threadIdx.x & 63;
    const float* wr = w + (size_t)row * DIMS;
    float a = wr[lane];
    float b = wr[lane + 64];
    float v = a * a + b * b;
    #pragma unroll
    for (int off = 32; off > 0; off >>= 1) v += __shfl_down(v, off, 64);
    if (lane == 0) wsq[row] = v;
}

// async-stage one B chunk: 16 d-rows x 256 codes from wt into LDS (linear, row-major)
__device__ __forceinline__ void stageB(const float* __restrict__ wtst,
                                       float* dst, int ct, int dbase, int t) {
    int lane = t & 63;
    int wv   = t >> 6;
    const float* gp = wtst + (size_t)(dbase + wv) * KC + ct * 256 + lane * 4;
    float* lp = dst + wv * 256;          // wave-uniform base
    #pragma unroll
    for (int r = 0; r < 4; ++r) {
        __builtin_amdgcn_global_load_lds((gbl_f*)(gp + (size_t)r * 4 * KC),
                                         (lds_f*)(lp + r * 4 * 256), 16, 0, 0);
    }
}

__global__ __launch_bounds__(256, 2)
void rvq_stage(const float* __restrict__ rin,
               float* __restrict__ rout,
               const float* __restrict__ wst,     // [K][D] this stage
               const float* __restrict__ wtst,    // [D][K] this stage
               const float* __restrict__ wsqst,   // [K]
               float* __restrict__ codes_out,
               float* __restrict__ rm0,           // replica0 rm accumulator (this stage)
               float* __restrict__ rmws,          // ws replica base (this stage)
               float* __restrict__ cc0,
               float* __restrict__ ccws,
               int repmask,                       // R-1
               int stage)
{
    __shared__ float A[DIMS * 64];       // 32 KB, [d][tok] XOR-quad swizzled
    __shared__ float BP[2][16 * 256];    // 32 KB dbuf; reused as w-tile in epilogue
    __shared__ float red_d[4 * 64];
    __shared__ int   red_k[4 * 64];
    __shared__ int   kbest[64];

    const int t    = threadIdx.x;
    const int tg   = t & 7;              // 8 token-groups of 8 tokens
    const int cgr  = t >> 3;             // 32 code-groups of 8 codes
    const int tok0 = blockIdx.x * 64;

    // ---- stage A: 64 tok x 128 d, coalesced read, swizzled transposed write
    #pragma unroll
    for (int q = 0; q < 8; ++q) {
        int idx = q * 256 + t;           // 2048 float4s
        int tok = idx >> 5;
        int dq  = idx & 31;
        float4 v = *reinterpret_cast<const float4*>(rin + (size_t)(tok0 + tok) * DIMS + dq * 4);
        int base = ((((tok >> 2) ^ dq) & 15) << 2) + (tok & 3);
        A[(dq * 4 + 0) * 64 + base] = v.x;
        A[(dq * 4 + 1) * 64 + base] = v.y;
        A[(dq * 4 + 2) * 64 + base] = v.z;
        A[(dq * 4 + 3) * 64 + base] = v.w;
    }
    stageB(wtst, &BP[0][0], 0, 0, t);
    __syncthreads();

    float best[8];
    int   bkst[8];
    #pragma unroll
    for (int i = 0; i < 8; ++i) { best[i] = INFINITY; bkst[i] = 0; }

    const float4* A4 = reinterpret_cast<const float4*>(A);
    int buf = 0;

    for (int ct = 0; ct < 4; ++ct) {
        float acc[8][8];
        #pragma unroll
        for (int i = 0; i < 8; ++i)
            #pragma unroll
            for (int j = 0; j < 8; ++j) acc[i][j] = 0.0f;

        for (int dch = 0; dch < 8; ++dch) {
            // prefetch next chunk
            if (!(ct == 3 && dch == 7)) {
                int nct = ct, ndb = (dch + 1) * 16;
                if (ndb == 128) { nct = ct + 1; ndb = 0; }
                stageB(wtst, &BP[buf ^ 1][0], nct, ndb, t);
            }
            // compute current chunk: d = dch*16 .. +16
            #pragma unroll
            for (int dl = 0; dl < 16; ++dl) {
                const int d  = dch * 16 + dl;
                const int dq = d >> 2;
                float4 a0 = A4[d * 16 + (((2 * tg)     ^ dq) & 15)];
                float4 a1 = A4[d * 16 + (((2 * tg + 1) ^ dq) & 15)];
                const float4* Brow = reinterpret_cast<const float4*>(&BP[buf][dl * 256]);
                float4 b0 = Brow[cgr * 2];
                float4 b1 = Brow[cgr * 2 + 1];
                const float a[8]  = {a0.x,a0.y,a0.z,a0.w, a1.x,a1.y,a1.z,a1.w};
                const float bb[8] = {b0.x,b0.y,b0.z,b0.w, b1.x,b1.y,b1.z,b1.w};
                #pragma unroll
                for (int i = 0; i < 8; ++i)
                    #pragma unroll
                    for (int j = 0; j < 8; ++j)
                        acc[i][j] = fmaf(a[i], bb[j], acc[i][j]);
            }
            __syncthreads();
            buf ^= 1;
        }
        // NOTE: buf flipped an even number of times in the dch loop, so it is
        // already back to its start-of-ct value; the (ct,0) chunk for the next
        // ct was staged into BP[buf^1] at dch==7 and lands in BP[buf] after the
        // final flip. No extra adjustment. (R3's extra flip here was the bug.)

        // dist + running argmin for this ct's 256 codes
        float4 wq0 = *reinterpret_cast<const float4*>(wsqst + ct * 256 + cgr * 8);
        float4 wq1 = *reinterpret_cast<const float4*>(wsqst + ct * 256 + cgr * 8 + 4);
        const float wqa[8] = {wq0.x,wq0.y,wq0.z,wq0.w, wq1.x,wq1.y,wq1.z,wq1.w};
        #pragma unroll
        for (int j = 0; j < 8; ++j) {
            int code = ct * 256 + cgr * 8 + j;
            #pragma unroll
            for (int i = 0; i < 8; ++i) {
                float dist = wqa[j] - 2.0f * acc[i][j];
                if (dist < best[i]) { best[i] = dist; bkst[i] = code; }
            }
        }
    }

    // ---- argmin reduce across the 8 in-wave code-groups sharing each tg
    #pragma unroll
    for (int i = 0; i < 8; ++i) {
        float bd = best[i];
        int   bk = bkst[i];
        #pragma unroll
        for (int m = 8; m < 64; m <<= 1) {
            float od = __shfl_xor(bd, m, 64);
            int   ok = __shfl_xor(bk, m, 64);
            if (od < bd || (od == bd && ok < bk)) { bd = od; bk = ok; }
        }
        best[i] = bd; bkst[i] = bk;
    }
    const int wid = t >> 6;
    if ((t & 56) == 0) {                  // lane per (wave, tg)
        #pragma unroll
        for (int i = 0; i < 8; ++i) {
            red_d[wid * 64 + tg * 8 + i] = best[i];
            red_k[wid * 64 + tg * 8 + i] = bkst[i];
        }
    }
    __syncthreads();

    const int rep = blockIdx.x & repmask;
    float* rmdst = rep ? rmws + (size_t)(rep - 1) * REPSTRIDE : rm0;
    float* ccdst = rep ? ccws + (size_t)(rep - 1) * REPSTRIDE : cc0;

    if (t < 64) {
        float bd = red_d[t];
        int   bk = red_k[t];
        #pragma unroll
        for (int w = 1; w < 4; ++w) {
            float od = red_d[w * 64 + t];
            int   ok = red_k[w * 64 + t];
            if (od < bd || (od == bd && ok < bk)) { bd = od; bk = ok; }
        }
        kbest[t] = bk;
        codes_out[(size_t)(tok0 + t) * QST + stage] = (float)bk;
        atomicAdd(ccdst + bk, 1.0f);
    }
    __syncthreads();

    // ---- stage selected w rows into BP (same swizzled [d][tok] layout as A)
    {
        float* W = &BP[0][0];
        int row  = t >> 2;               // token 0..63
        int part = t & 3;                // d block of 32
        int k = kbest[row];
        const float4* wp = reinterpret_cast<const float4*>(wst + (size_t)k * DIMS + part * 32);
        #pragma unroll
        for (int i = 0; i < 8; ++i) {
            float4 v = wp[i];
            int d = part * 32 + i * 4;
            int base = ((((row >> 2) ^ (d >> 2)) & 15) << 2) + (row & 3);
            W[(d + 0) * 64 + base] = v.x;
            W[(d + 1) * 64 + base] = v.y;
            W[(d + 2) * 64 + base] = v.z;
            W[(d + 3) * 64 + base] = v.w;
        }
    }
    __syncthreads();

    // ---- update: rm += r_old ; r_new = r_old - w[k]
    const float* W = &BP[0][0];
    #pragma unroll
    for (int it = 0; it < 8; ++it) {
        int idx = it * 256 + t;          // 2048 float4 items
        int tok = idx >> 5;
        int dq  = idx & 31;
        int k   = kbest[tok];
        int base = ((((tok >> 2) ^ dq) & 15) << 2) + (tok & 3);
        int d0 = dq * 4;
        float r0 = A[(d0 + 0) * 64 + base];
        float r1 = A[(d0 + 1) * 64 + base];
        float r2 = A[(d0 + 2) * 64 + base];
        float r3 = A[(d0 + 3) * 64 + base];
        float w0 = W[(d0 + 0) * 64 + base];
        float w1 = W[(d0 + 1) * 64 + base];
        float w2 = W[(d0 + 2) * 64 + base];
        float w3 = W[(d0 + 3) * 64 + base];
        float* rmp = rmdst + (size_t)k * DIMS + d0;
        atomicAdd(rmp + 0, r0);
        atomicAdd(rmp + 1, r1);
        atomicAdd(rmp + 2, r2);
        atomicAdd(rmp + 3, r3);
        float4 o = {r0 - w0, r1 - w1, r2 - w2, r3 - w3};
        *reinterpret_cast<float4*>(rout + (size_t)(tok0 + tok) * DIMS + d0) = o;
    }
}

// quantized = x - r (in place) + commitment-loss partials
__global__ void rvq_quant_loss(const float* __restrict__ x,
                               float* __restrict__ rq,
                               float* __restrict__ loss_acc) {
    __shared__ float ws[4];
    int tid = blockIdx.x * 256 + threadIdx.x;
    float lsum = 0.0f;
    #pragma unroll
    for (int rep = 0; rep < 4; ++rep) {
        size_t q = (size_t)tid + (size_t)rep * 262144;
        float4 rv = *reinterpret_cast<float4*>(rq + q * 4);
        float4 xv = *reinterpret_cast<const float4*>(x + q * 4);
        lsum += rv.x*rv.x + rv.y*rv.y + rv.z*rv.z + rv.w*rv.w;
        float4 o = {xv.x - rv.x, xv.y - rv.y, xv.z - rv.z, xv.w - rv.w};
        *reinterpret_cast<float4*>(rq + q * 4) = o;
    }
    #pragma unroll
    for (int off = 32; off > 0; off >>= 1) lsum += __shfl_down(lsum, off, 64);
    if ((threadIdx.x & 63) == 0) ws[threadIdx.x >> 6] = lsum;
    __syncthreads();
    if (threadIdx.x == 0) atomicAdd(loss_acc, ws[0] + ws[1] + ws[2] + ws[3]);
}

__global__ void rvq_fin_cc(const float* __restrict__ cc_in,
                           float* __restrict__ cc_io,
                           const float* __restrict__ ws_cc,  // ws + WS_REP + SZ_W
                           int nrep_m1,
                           const float* __restrict__ loss_acc,
                           float* __restrict__ loss_out) {
    int i = blockIdx.x * 256 + threadIdx.x;   // 8192
    float a = cc_io[i];
    for (int r = 0; r < nrep_m1; ++r) a += ws_cc[(size_t)r * REPSTRIDE + i];
    cc_io[i] = cc_in[i] * 0.99f + (a / 32768.0f) * 0.01f;
    if (i == 0) loss_out[0] = loss_acc[0] / (float)(NTOK * DIMS);
}

__global__ void rvq_fin_rmw(const float* __restrict__ rm_in,
                            float* __restrict__ rm_io,
                            const float* __restrict__ ws_rm,  // ws + WS_REP
                            int nrep_m1,
                            float* __restrict__ w_out,
                            const float* __restrict__ cc_fin) {
    int i = blockIdx.x * 256 + threadIdx.x;   // 1,048,576
    float a = rm_io[i];
    for (int r = 0; r < nrep_m1; ++r) a += ws_rm[(size_t)r * REPSTRIDE + i];
    float nrm = rm_in[i] * 0.99f + (a / 32768.0f) * 0.01f;
    rm_io[i] = nrm;
    w_out[i] = nrm / (1e-10f + cc_fin[i >> 7]);
}

extern "C" void kernel_launch(void* const* d_in, const int* in_sizes, int n_in,
                              void* d_out, int out_size, void* d_ws, size_t ws_size,
                              hipStream_t stream) {
    const float* x   = (const float*)d_in[0];
    const float* w   = (const float*)d_in[1];
    const float* rm  = (const float*)d_in[2];
    const float* cc  = (const float*)d_in[3];
    float* out   = (float*)d_out;
    float* quant = out;                    // residual buffer during stages
    float* codes = out + OFF_CODES;
    float* loss  = out + OFF_LOSS;
    float* wout  = out + OFF_W;            // holds wt until rvq_fin_rmw
    float* rmout = out + OFF_RM;
    float* ccout = out + OFF_CC;
    float* wsf   = (float*)d_ws;
    float* lacc  = wsf;
    float* wsq   = wsf + WS_WSQ;
    float* wt    = wout;

    int R = 1;
    if (ws_size >= (WS_REP + 3 * REPSTRIDE) * sizeof(float)) R = 4;
    else if (ws_size >= (WS_REP + 1 * REPSTRIDE) * sizeof(float)) R = 2;

    hipMemsetAsync(rmout, 0, (size_t)(SZ_W + QST * KC) * sizeof(float), stream);
    hipMemsetAsync(d_ws, 0, 16 * sizeof(float), stream);
    if (R > 1)
        hipMemsetAsync(wsf + WS_REP, 0, (size_t)(R - 1) * REPSTRIDE * sizeof(float), stream);

    rvq_transpose<<<1024, 256, 0, stream>>>(w, wt);
    rvq_wsq<<<QST * KC / 4, 256, 0, stream>>>(w, wsq);

    for (int s = 0; s < QST; ++s) {
        const float* rin = (s == 0) ? x : quant;
        rvq_stage<<<NTOK / 64, 256, 0, stream>>>(
            rin, quant,
            w  + (size_t)s * KC * DIMS,
            wt + (size_t)s * KC * DIMS,
            wsq + (size_t)s * KC,
            codes,
            rmout + (size_t)s * KC * DIMS,
            wsf + WS_REP + (size_t)s * KC * DIMS,
            ccout + (size_t)s * KC,
            wsf + WS_REP + SZ_W + (size_t)s * KC,
            R - 1,
            s);
    }

    rvq_quant_loss<<<1024, 256, 0, stream>>>(x, quant, lacc);
    rvq_fin_cc<<<QST * KC / 256, 256, 0, stream>>>(cc, ccout, wsf + WS_REP + SZ_W, R - 1, lacc, loss);
    rvq_fin_rmw<<<SZ_W / 256, 256, 0, stream>>>(rm, rmout, wsf + WS_REP, R - 1, wout, ccout);
}